// Round 14
// baseline (52.873 us; speedup 1.0000x reference)
//
#include <hip/hip_runtime.h>
#include <hip/hip_bf16.h>

#define D 128            // D_IN == D_OUT == 128
#define RPB 16           // rows per bucket
#define NBMAX 640        // max buckets (N<=10240)
#define EPB 8192         // edges per chunk in stage sort
#define CAP 2048         // fixed eb stride per bucket (mean 1024, +32 sigma)
#define OVFCAP 65536     // overflow list capacity (never used in practice)
#define EPS 1e-8f

typedef unsigned int uint32;
typedef unsigned short uint16;

__device__ __forceinline__ uint32 f2bf_rne(float f) {
    uint32 u = __float_as_uint(f);
    return (u + 0x7fffu + ((u >> 16) & 1u)) >> 16;   // round-nearest-even
}
__device__ __forceinline__ float bfl(uint32 u) { return __uint_as_float(u << 16); }
__device__ __forceinline__ float bfh(uint32 u) { return __uint_as_float(u & 0xffff0000u); }

// ---------------- zero: replaces hipMemsetAsync ----------------

__global__ __launch_bounds__(256) void k_zero(int* __restrict__ bcur, int n) {
    int i = blockIdx.x * 256 + threadIdx.x;
    if (i < n) bcur[i] = 0;      // covers bcur[NB] + ovfn (last element)
}

// ---------------- stage: role-split blocks ----------------
// blocks [0, nchunk): counting-sort an EPB edge chunk into fixed-stride eb
// blocks [nchunk, ..): pack xb (and WT in the first 16 of them)
// xb[c*64 + j] packs features (j, j+64) of node c

__global__ __launch_bounds__(512) void k_stage(
        const float* __restrict__ x, const int* __restrict__ ei,
        const float* __restrict__ Wm, const float* __restrict__ Wu,
        uint32* __restrict__ xb, uint32* __restrict__ WTmb, uint32* __restrict__ WTub,
        int* __restrict__ bcur, int* __restrict__ ovfn, uint32* __restrict__ ovf,
        uint32* __restrict__ eb, int E_, int NX, int NB, int nchunk) {
    const int tid = threadIdx.x;

    if (blockIdx.x >= nchunk) {
        // ---- pack role ----
        int i = (blockIdx.x - nchunk) * 512 + tid;
        if (i < NX) {
            int c = i >> 6, j = i & 63;
            float lo = x[c * D + j];
            float hi = x[c * D + j + 64];
            xb[i] = f2bf_rne(lo) | (f2bf_rne(hi) << 16);
        }
        if (i < 64 * D) {
            int k2 = i >> 7, f = i & 127;
            WTmb[i] = f2bf_rne(Wm[f * D + 2 * k2]) | (f2bf_rne(Wm[f * D + 2 * k2 + 1]) << 16);
            WTub[i] = f2bf_rne(Wu[f * D + 2 * k2]) | (f2bf_rne(Wu[f * D + 2 * k2 + 1]) << 16);
        }
        return;
    }

    // ---- sort role ----
    __shared__ int h[NBMAX];
    __shared__ int off[NBMAX];
    __shared__ int bias[NBMAX];
    __shared__ uint32 stg[EPB];

    const int base = blockIdx.x * EPB;
    const int nE = min(EPB, E_ - base);

    for (int i = tid; i < NB; i += 512) h[i] = 0;
    __syncthreads();

    for (int i = tid; i < nE; i += 512)
        atomicAdd(&h[ei[base + i] >> 4], 1);
    __syncthreads();

    if (tid < 64) {   // exclusive scan of h by one wave (10 bins per lane)
        int b0 = tid * 10;
        int loc[10];
        int lsum = 0;
        #pragma unroll
        for (int j = 0; j < 10; ++j) {
            int b = b0 + j;
            int v = (b < NB) ? h[b] : 0;
            loc[j] = lsum;
            lsum += v;
        }
        int run = lsum;
        #pragma unroll
        for (int o = 1; o < 64; o <<= 1) {
            int u = __shfl_up(run, o);
            if (tid >= o) run += u;
        }
        int excl = run - lsum;
        #pragma unroll
        for (int j = 0; j < 10; ++j) {
            int b = b0 + j;
            if (b < NB) off[b] = excl + loc[j];
        }
    }
    __syncthreads();

    // reserve global ranges per bucket (fixed stride: bucket b starts at b*CAP)
    for (int b = tid; b < NB; b += 512) {
        int c = h[b];
        if (c) {
            int g = atomicAdd(&bcur[b], c);
            bias[b] = (b << 11) + g - off[b];
        }
    }
    __syncthreads();

    // scatter into bucket-sorted staging
    for (int i = tid; i < nE; i += 512) {
        int r = ei[base + i];
        int c = ei[E_ + base + i];
        int b = r >> 4;
        int p = atomicAdd(&off[b], 1);
        stg[p] = ((uint32)r << 16) | (uint32)c;
    }
    __syncthreads();

    // linear write-out; positions beyond CAP spill to overflow list
    for (int i = tid; i < nE; i += 512) {
        uint32 v = stg[i];
        int b = v >> 20;                  // row = v>>16, bucket = row>>4
        int p = bias[b] + i;
        if (p - (b << 11) < CAP) {
            eb[p] = v;
        } else {
            int o = atomicAdd(ovfn, 1);
            if (o < OVFCAP) ovf[o] = v;
        }
    }
}

// ---------------- fused: row sort + quad bf16 gather + 2-level matvecs -------
// one block per bucket (16 rows); 512 threads = 8 waves.
// gather: wave owns 2 rows, 4 edges per iteration (16 lanes x uint4 each).
// matvec: wave = (row-half wv>>2) x (k-quarter wv&3); the two waves sharing a
// k-quarter read identical W addresses (L1 hits) -> W L2 traffic halves.

__global__ __launch_bounds__(512) void k_fused(
        const uint32* __restrict__ xb, const int* __restrict__ bcur,
        const uint32* __restrict__ eb,
        const int* __restrict__ ovfn, const uint32* __restrict__ ovf,
        const uint32* __restrict__ WTmb, const float* __restrict__ bm,
        const uint32* __restrict__ WTub, const float* __restrict__ bu,
        float* __restrict__ out, int N_) {
    __shared__ float a_lds[RPB][D];          // 8 KB aggregated sums
    __shared__ float o_lds[RPB][D];          // 8 KB intermediate
    __shared__ float p_lds[8][RPB / 2][D];   // 32 KB matvec partials (aliased)
    __shared__ int hist16[RPB], cur16[RPB], rst[RPB], dcnt[RPB];

    uint32* ebl = (uint32*)p_lds;            // [CAP]  8 KB  (sort phase only)
    uint16* stg = (uint16*)(ebl + CAP);      // [CAP]  4 KB  (sort+gather phase)

    const int tid  = threadIdx.x;
    const int lane = tid & 63;
    const int wv   = tid >> 6;

    for (int i = tid; i < RPB * D; i += 512) ((float*)a_lds)[i] = 0.f;
    if (tid < RPB) { hist16[tid] = 0; cur16[tid] = 0; }
    __syncthreads();

    const int ebase = blockIdx.x << 11;
    const int cnt   = bcur[blockIdx.x];
    const int cntc  = min(cnt, CAP);

    // pass A: cache edges in LDS + ballot row histogram
    {
        int cnt_loc = 0;
        for (int i0 = 0; i0 < cntc; i0 += 512) {
            int i = i0 + tid;
            bool valid = i < cntc;
            uint32 v = valid ? eb[ebase + i] : 0u;
            if (valid) ebl[i] = v;
            int myr = (v >> 16) & 15;
            #pragma unroll
            for (int r = 0; r < RPB; ++r) {
                unsigned long long m = __ballot(valid && (myr == r));
                if (lane == r) cnt_loc += __popcll(m);
            }
        }
        if (lane < RPB && cnt_loc) atomicAdd(&hist16[lane], cnt_loc);
    }
    __syncthreads();
    if (tid == 0) {
        int run = 0;
        #pragma unroll
        for (int r = 0; r < RPB; ++r) { rst[r] = run; run += hist16[r]; dcnt[r] = hist16[r]; }
    }
    __syncthreads();

    // pass B: scatter cols into row-sorted staging (from LDS)
    for (int i = tid; i < cntc; i += 512) {
        uint32 v = ebl[i];
        int r = (v >> 16) & 15;
        int p = rst[r] + atomicAdd(&cur16[r], 1);
        stg[p] = (uint16)(v & 0xffffu);
    }
    // overflow path (cnt > CAP: never taken in practice; correct + slow)
    if (cnt > CAP) {
        int no = min(*ovfn, OVFCAP);
        for (int ii = wv * 64; ii < no; ii += 512) {
            int m = min(64, no - ii);
            uint32 v_l = 0;
            if (lane < m) {
                v_l = ovf[ii + lane];
                if ((v_l >> 20) == (uint32)blockIdx.x)
                    atomicAdd(&dcnt[(v_l >> 16) & 15], 1);
            }
            for (int t = 0; t < m; ++t) {
                uint32 ev = __builtin_amdgcn_readlane(v_l, t);
                if ((ev >> 20) != (uint32)blockIdx.x) continue;
                uint32 v = xb[((ev & 0xffffu) << 6) + lane];
                int r = (ev >> 16) & 15;
                atomicAdd(&a_lds[r][lane],      bfl(v));
                atomicAdd(&a_lds[r][lane + 64], bfh(v));
            }
        }
    }
    __syncthreads();

    // ---- quad gather: wave owns rows {2wv, 2wv+1}; 4 edges per iteration ----
    const int q  = lane >> 4;
    const int lf = lane & 15;
    const uint4* __restrict__ xb4 = (const uint4*)xb;   // row = 16 uint4

    #pragma unroll
    for (int j = 0; j < 2; ++j) {
        int r  = wv * 2 + j;
        int lo = rst[r];
        int n  = hist16[r];
        int nq = n >> 2;

        float4 aL = make_float4(0.f, 0.f, 0.f, 0.f);
        float4 aH = make_float4(0.f, 0.f, 0.f, 0.f);

        int it = 0;
        for (; it + 4 <= nq; it += 4) {
            int cA = stg[lo + 4 * it + q];
            int cB = stg[lo + 4 * (it + 1) + q];
            int cC = stg[lo + 4 * (it + 2) + q];
            int cD = stg[lo + 4 * (it + 3) + q];
            uint4 vA = xb4[(cA << 4) + lf];
            uint4 vB = xb4[(cB << 4) + lf];
            uint4 vC = xb4[(cC << 4) + lf];
            uint4 vD = xb4[(cD << 4) + lf];
            aL.x += bfl(vA.x); aH.x += bfh(vA.x);
            aL.y += bfl(vA.y); aH.y += bfh(vA.y);
            aL.z += bfl(vA.z); aH.z += bfh(vA.z);
            aL.w += bfl(vA.w); aH.w += bfh(vA.w);
            aL.x += bfl(vB.x); aH.x += bfh(vB.x);
            aL.y += bfl(vB.y); aH.y += bfh(vB.y);
            aL.z += bfl(vB.z); aH.z += bfh(vB.z);
            aL.w += bfl(vB.w); aH.w += bfh(vB.w);
            aL.x += bfl(vC.x); aH.x += bfh(vC.x);
            aL.y += bfl(vC.y); aH.y += bfh(vC.y);
            aL.z += bfl(vC.z); aH.z += bfh(vC.z);
            aL.w += bfl(vC.w); aH.w += bfh(vC.w);
            aL.x += bfl(vD.x); aH.x += bfh(vD.x);
            aL.y += bfl(vD.y); aH.y += bfh(vD.y);
            aL.z += bfl(vD.z); aH.z += bfh(vD.z);
            aL.w += bfl(vD.w); aH.w += bfh(vD.w);
        }
        for (; it < nq; ++it) {
            int c = stg[lo + 4 * it + q];
            uint4 v = xb4[(c << 4) + lf];
            aL.x += bfl(v.x); aH.x += bfh(v.x);
            aL.y += bfl(v.y); aH.y += bfh(v.y);
            aL.z += bfl(v.z); aH.z += bfh(v.z);
            aL.w += bfl(v.w); aH.w += bfh(v.w);
        }
        int rem = n & 3;
        if (q < rem) {     // tail edges handled one per quarter
            int c = stg[lo + 4 * nq + q];
            uint4 v = xb4[(c << 4) + lf];
            aL.x += bfl(v.x); aH.x += bfh(v.x);
            aL.y += bfl(v.y); aH.y += bfh(v.y);
            aL.z += bfl(v.z); aH.z += bfh(v.z);
            aL.w += bfl(v.w); aH.w += bfh(v.w);
        }
        // combine quarters
        aL.x += __shfl_xor(aL.x, 16); aL.x += __shfl_xor(aL.x, 32);
        aL.y += __shfl_xor(aL.y, 16); aL.y += __shfl_xor(aL.y, 32);
        aL.z += __shfl_xor(aL.z, 16); aL.z += __shfl_xor(aL.z, 32);
        aL.w += __shfl_xor(aL.w, 16); aL.w += __shfl_xor(aL.w, 32);
        aH.x += __shfl_xor(aH.x, 16); aH.x += __shfl_xor(aH.x, 32);
        aH.y += __shfl_xor(aH.y, 16); aH.y += __shfl_xor(aH.y, 32);
        aH.z += __shfl_xor(aH.z, 16); aH.z += __shfl_xor(aH.z, 32);
        aH.w += __shfl_xor(aH.w, 16); aH.w += __shfl_xor(aH.w, 32);
        if (q == 0) {      // exclusive (row, lf) per lane: plain RMW
            float4 o0 = *(const float4*)&a_lds[r][4 * lf];
            float4 o1 = *(const float4*)&a_lds[r][4 * lf + 64];
            o0.x += aL.x; o0.y += aL.y; o0.z += aL.z; o0.w += aL.w;
            o1.x += aH.x; o1.y += aH.y; o1.z += aH.z; o1.w += aH.w;
            *(float4*)&a_lds[r][4 * lf]      = o0;
            *(float4*)&a_lds[r][4 * lf + 64] = o1;
        }
    }
    __syncthreads();

    // ---- matvec 1: wave = row-half hh x k-quarter kq; covers 8 rows ----
    const int f0 = lane, f1 = lane + 64;
    const int hh  = wv >> 2;            // 0/1: rows hh*8 .. hh*8+7
    const int k0b = (wv & 3) * 32;      // k-slice

    float acc0[8], acc1[8];
    #pragma unroll
    for (int r = 0; r < 8; ++r) { acc0[r] = 0.f; acc1[r] = 0.f; }

    #pragma unroll
    for (int kk = 0; kk < 32; kk += 4) {
        int k2 = (k0b + kk) >> 1;
        uint32 wm00 = WTmb[k2 * D + f0];
        uint32 wm01 = WTmb[(k2 + 1) * D + f0];
        uint32 wm10 = WTmb[k2 * D + f1];
        uint32 wm11 = WTmb[(k2 + 1) * D + f1];
        float w00l = bfl(wm00), w00h = bfh(wm00), w01l = bfl(wm01), w01h = bfh(wm01);
        float w10l = bfl(wm10), w10h = bfh(wm10), w11l = bfl(wm11), w11h = bfh(wm11);
        #pragma unroll
        for (int r = 0; r < 8; ++r) {
            float4 a4 = *(const float4*)&a_lds[hh * 8 + r][k0b + kk];
            acc0[r] += a4.x * w00l + a4.y * w00h + a4.z * w01l + a4.w * w01h;
            acc1[r] += a4.x * w10l + a4.y * w10h + a4.z * w11l + a4.w * w11h;
        }
    }
    #pragma unroll
    for (int r = 0; r < 8; ++r) {
        p_lds[wv][r][f0] = acc0[r];
        p_lds[wv][r][f1] = acc1[r];
    }
    __syncthreads();

    // ---- reduce 1 + bias + mean: thread -> (row, 4 features) ----
    {
        int row = tid >> 5;                 // 0..15
        int fq  = (tid & 31) * 4;
        int pb  = (row >> 3) * 4;           // partial base for this row-half
        int r8  = row & 7;
        float4 s0 = *(const float4*)&p_lds[pb + 0][r8][fq];
        float4 s1 = *(const float4*)&p_lds[pb + 1][r8][fq];
        float4 s2 = *(const float4*)&p_lds[pb + 2][r8][fq];
        float4 s3 = *(const float4*)&p_lds[pb + 3][r8][fq];
        float cntf = (float)dcnt[row];
        float inv = 1.0f / (cntf + EPS);
        float4 b4 = *(const float4*)&bm[fq];
        float4 o;
        o.x = (s0.x + s1.x + s2.x + s3.x + cntf * b4.x) * inv;
        o.y = (s0.y + s1.y + s2.y + s3.y + cntf * b4.y) * inv;
        o.z = (s0.z + s1.z + s2.z + s3.z + cntf * b4.z) * inv;
        o.w = (s0.w + s1.w + s2.w + s3.w + cntf * b4.w) * inv;
        *(float4*)&o_lds[row][fq] = o;
    }
    __syncthreads();

    // ---- matvec 2 ----
    #pragma unroll
    for (int r = 0; r < 8; ++r) { acc0[r] = 0.f; acc1[r] = 0.f; }

    #pragma unroll
    for (int kk = 0; kk < 32; kk += 4) {
        int k2 = (k0b + kk) >> 1;
        uint32 wu00 = WTub[k2 * D + f0];
        uint32 wu01 = WTub[(k2 + 1) * D + f0];
        uint32 wu10 = WTub[k2 * D + f1];
        uint32 wu11 = WTub[(k2 + 1) * D + f1];
        float w00l = bfl(wu00), w00h = bfh(wu00), w01l = bfl(wu01), w01h = bfh(wu01);
        float w10l = bfl(wu10), w10h = bfh(wu10), w11l = bfl(wu11), w11h = bfh(wu11);
        #pragma unroll
        for (int r = 0; r < 8; ++r) {
            float4 a4 = *(const float4*)&o_lds[hh * 8 + r][k0b + kk];
            acc0[r] += a4.x * w00l + a4.y * w00h + a4.z * w01l + a4.w * w01h;
            acc1[r] += a4.x * w10l + a4.y * w10h + a4.z * w11l + a4.w * w11h;
        }
    }
    __syncthreads();   // reduce-1 reads of p_lds complete before rewrite
    #pragma unroll
    for (int r = 0; r < 8; ++r) {
        p_lds[wv][r][f0] = acc0[r];
        p_lds[wv][r][f1] = acc1[r];
    }
    __syncthreads();

    // ---- reduce 2 + bias + row-norm + store ----
    {
        int row = tid >> 5;
        int fq  = (tid & 31) * 4;
        int pb  = (row >> 3) * 4;
        int r8  = row & 7;
        float4 s0 = *(const float4*)&p_lds[pb + 0][r8][fq];
        float4 s1 = *(const float4*)&p_lds[pb + 1][r8][fq];
        float4 s2 = *(const float4*)&p_lds[pb + 2][r8][fq];
        float4 s3 = *(const float4*)&p_lds[pb + 3][r8][fq];
        float4 b4 = *(const float4*)&bu[fq];
        float4 t;
        t.x = s0.x + s1.x + s2.x + s3.x + b4.x;
        t.y = s0.y + s1.y + s2.y + s3.y + b4.y;
        t.z = s0.z + s1.z + s2.z + s3.z + b4.z;
        t.w = s0.w + s1.w + s2.w + s3.w + b4.w;
        float ss = t.x * t.x + t.y * t.y + t.z * t.z + t.w * t.w;
        #pragma unroll
        for (int o = 16; o > 0; o >>= 1) ss += __shfl_xor(ss, o);
        float scale = 1.0f / (sqrtf(ss) + EPS);
        int n = blockIdx.x * RPB + row;
        if (n < N_) {
            float4 w;
            w.x = t.x * scale; w.y = t.y * scale; w.z = t.z * scale; w.w = t.w * scale;
            ((float4*)out)[n * 32 + (tid & 31)] = w;
        }
    }
}

// ---------------- launch ----------------

extern "C" void kernel_launch(void* const* d_in, const int* in_sizes, int n_in,
                              void* d_out, int out_size, void* d_ws, size_t ws_size,
                              hipStream_t stream) {
    const float* x  = (const float*)d_in[0];
    const int*   ei = (const int*)d_in[1];
    const float* Wm = (const float*)d_in[2];
    const float* bm = (const float*)d_in[3];
    const float* Wu = (const float*)d_in[4];
    const float* bu = (const float*)d_in[5];
    float* out = (float*)d_out;

    const int N_ = in_sizes[0] / D;        // 10000
    const int E_ = in_sizes[1] / 2;        // 640000
    const int NX = N_ * (D / 2);           // packed x pairs
    const int NB = (N_ + RPB - 1) / RPB;   // 625 buckets

    uint32* xb   = (uint32*)d_ws;                 // NX          (16B aligned)
    uint32* eb   = xb + NX;                       // NB*CAP
    uint32* WTmb = eb + (size_t)NB * CAP;         // 64*128
    uint32* WTub = WTmb + 64 * D;                 // 64*128
    int*    bcur = (int*)(WTub + 64 * D);         // NB
    int*    ovfn = bcur + NB;                     // 1
    uint32* ovf  = (uint32*)(ovfn + 1);           // OVFCAP

    k_zero<<<(NB + 1 + 255) / 256, 256, 0, stream>>>(bcur, NB + 1);

    const int nchunk = (E_ + EPB - 1) / EPB;          // 79
    const int npack  = (NX + 511) / 512;              // 1250
    k_stage<<<nchunk + npack, 512, 0, stream>>>(
        x, ei, Wm, Wu, xb, WTmb, WTub, bcur, ovfn, ovf, eb, E_, NX, NB, nchunk);

    k_fused<<<NB, 512, 0, stream>>>(xb, bcur, eb, ovfn, ovf,
                                    WTmb, bm, WTub, bu, out, N_);
}

// Round 15
// 49.137 us; speedup vs baseline: 1.0760x; 1.0760x over previous
//
#include <hip/hip_runtime.h>
#include <hip/hip_bf16.h>

#define D 128            // D_IN == D_OUT == 128
#define RPB 8            // rows per bucket
#define NBMAX 1280       // max buckets (N<=10240)
#define EPB 8192         // edges per chunk in stage sort
#define CAP 1024         // fixed eb stride per bucket (mean 512, +22 sigma)
#define OVFCAP 65536     // overflow list capacity (never used in practice)
#define EPS 1e-8f

typedef unsigned int uint32;
typedef unsigned short uint16;

__device__ __forceinline__ uint32 f2bf_rne(float f) {
    uint32 u = __float_as_uint(f);
    return (u + 0x7fffu + ((u >> 16) & 1u)) >> 16;   // round-nearest-even
}
__device__ __forceinline__ float bfl(uint32 u) { return __uint_as_float(u << 16); }
__device__ __forceinline__ float bfh(uint32 u) { return __uint_as_float(u & 0xffff0000u); }

// ---------------- zero: replaces hipMemsetAsync (runtime fill ~40us) ----------

__global__ __launch_bounds__(256) void k_zero(int* __restrict__ bcur, int n) {
    int i = blockIdx.x * 256 + threadIdx.x;
    if (i < n) bcur[i] = 0;      // covers bcur[NB] + ovfn (last element)
}

// ---------------- stage: role-split blocks ----------------
// blocks [0, nchunk): counting-sort an EPB edge chunk into fixed-stride eb
// blocks [nchunk, ..): pack xb (and WT in the first 16 of them)
// xb[c*64 + j] packs features (j, j+64) of node c

__global__ __launch_bounds__(512) void k_stage(
        const float* __restrict__ x, const int* __restrict__ ei,
        const float* __restrict__ Wm, const float* __restrict__ Wu,
        uint32* __restrict__ xb, uint32* __restrict__ WTmb, uint32* __restrict__ WTub,
        int* __restrict__ bcur, int* __restrict__ ovfn, uint32* __restrict__ ovf,
        uint32* __restrict__ eb, int E_, int NX, int NB, int nchunk) {
    const int tid = threadIdx.x;

    if (blockIdx.x >= nchunk) {
        // ---- pack role ----
        int i = (blockIdx.x - nchunk) * 512 + tid;
        if (i < NX) {
            int c = i >> 6, j = i & 63;
            float lo = x[c * D + j];
            float hi = x[c * D + j + 64];
            xb[i] = f2bf_rne(lo) | (f2bf_rne(hi) << 16);
        }
        if (i < 64 * D) {
            int k2 = i >> 7, f = i & 127;
            WTmb[i] = f2bf_rne(Wm[f * D + 2 * k2]) | (f2bf_rne(Wm[f * D + 2 * k2 + 1]) << 16);
            WTub[i] = f2bf_rne(Wu[f * D + 2 * k2]) | (f2bf_rne(Wu[f * D + 2 * k2 + 1]) << 16);
        }
        return;
    }

    // ---- sort role ----
    __shared__ int h[NBMAX];
    __shared__ int off[NBMAX];
    __shared__ int bias[NBMAX];
    __shared__ uint32 stg[EPB];

    const int base = blockIdx.x * EPB;
    const int nE = min(EPB, E_ - base);

    for (int i = tid; i < NB; i += 512) h[i] = 0;
    __syncthreads();

    for (int i = tid; i < nE; i += 512)
        atomicAdd(&h[ei[base + i] >> 3], 1);
    __syncthreads();

    if (tid < 64) {   // exclusive scan of h by one wave (20 bins per lane)
        int b0 = tid * 20;
        int loc[20];
        int lsum = 0;
        #pragma unroll
        for (int j = 0; j < 20; ++j) {
            int b = b0 + j;
            int v = (b < NB) ? h[b] : 0;
            loc[j] = lsum;
            lsum += v;
        }
        int run = lsum;
        #pragma unroll
        for (int o = 1; o < 64; o <<= 1) {
            int u = __shfl_up(run, o);
            if (tid >= o) run += u;
        }
        int excl = run - lsum;
        #pragma unroll
        for (int j = 0; j < 20; ++j) {
            int b = b0 + j;
            if (b < NB) off[b] = excl + loc[j];
        }
    }
    __syncthreads();

    // reserve global ranges per bucket (fixed stride: bucket b starts at b*CAP)
    for (int b = tid; b < NB; b += 512) {
        int c = h[b];
        if (c) {
            int g = atomicAdd(&bcur[b], c);
            bias[b] = (b << 10) + g - off[b];
        }
    }
    __syncthreads();

    // scatter into bucket-sorted staging
    for (int i = tid; i < nE; i += 512) {
        int r = ei[base + i];
        int c = ei[E_ + base + i];
        int b = r >> 3;
        int p = atomicAdd(&off[b], 1);
        stg[p] = ((uint32)r << 16) | (uint32)c;
    }
    __syncthreads();

    // linear write-out; positions beyond CAP spill to overflow list
    for (int i = tid; i < nE; i += 512) {
        uint32 v = stg[i];
        int b = v >> 19;                  // row = v>>16, bucket = row>>3
        int p = bias[b] + i;
        if (p - (b << 10) < CAP) {
            eb[p] = v;
        } else {
            int o = atomicAdd(ovfn, 1);
            if (o < OVFCAP) ovf[o] = v;
        }
    }
}

// ---------------- fused: row sort + quad bf16 gather (8-deep MLP) + matvecs --
// one block per bucket (8 rows); 256 threads = 4 waves.
// gather: wave owns 2 rows, 4 edges per iteration (16 lanes x uint4 each),
//         unrolled x8 -> 8 independent uint4 loads in flight per wave.
// matvec: wave owns a 32-wide k-slice of ALL rows; partials reduced via LDS.

__global__ __launch_bounds__(256) void k_fused(
        const uint32* __restrict__ xb, const int* __restrict__ bcur,
        const uint32* __restrict__ eb,
        const int* __restrict__ ovfn, const uint32* __restrict__ ovf,
        const uint32* __restrict__ WTmb, const float* __restrict__ bm,
        const uint32* __restrict__ WTub, const float* __restrict__ bu,
        float* __restrict__ out, int N_) {
    __shared__ float a_lds[RPB][D];          // 4 KB aggregated sums
    __shared__ float o_lds[RPB][D];          // 4 KB intermediate
    __shared__ float p_lds[4][RPB][D];       // 16 KB matvec partials (aliased)
    __shared__ int hist8[RPB], cur8[RPB], rst[RPB], dcnt[RPB];

    uint32* ebl = (uint32*)p_lds;            // [CAP]  4 KB  (sort phase only)
    uint16* stg = (uint16*)(ebl + CAP);      // [CAP]  2 KB  (sort+gather phase)

    const int tid  = threadIdx.x;
    const int lane = tid & 63;
    const int wv   = tid >> 6;

    for (int i = tid; i < RPB * D; i += 256) ((float*)a_lds)[i] = 0.f;
    if (tid < RPB) { hist8[tid] = 0; cur8[tid] = 0; }
    __syncthreads();

    const int ebase = blockIdx.x << 10;
    const int cnt   = bcur[blockIdx.x];
    const int cntc  = min(cnt, CAP);

    // pass A: cache edges in LDS + ballot row histogram
    {
        int cnt_loc = 0;
        for (int i0 = 0; i0 < cntc; i0 += 256) {
            int i = i0 + tid;
            bool valid = i < cntc;
            uint32 v = valid ? eb[ebase + i] : 0u;
            if (valid) ebl[i] = v;
            int myr = (v >> 16) & 7;
            #pragma unroll
            for (int r = 0; r < RPB; ++r) {
                unsigned long long m = __ballot(valid && (myr == r));
                if (lane == r) cnt_loc += __popcll(m);
            }
        }
        if (lane < RPB && cnt_loc) atomicAdd(&hist8[lane], cnt_loc);
    }
    __syncthreads();
    if (tid == 0) {
        int run = 0;
        #pragma unroll
        for (int r = 0; r < RPB; ++r) { rst[r] = run; run += hist8[r]; dcnt[r] = hist8[r]; }
    }
    __syncthreads();

    // pass B: scatter cols into row-sorted staging (from LDS)
    for (int i = tid; i < cntc; i += 256) {
        uint32 v = ebl[i];
        int r = (v >> 16) & 7;
        int p = rst[r] + atomicAdd(&cur8[r], 1);
        stg[p] = (uint16)(v & 0xffffu);
    }
    // overflow path (cnt > CAP: never taken in practice; correct + slow)
    if (cnt > CAP) {
        int no = min(*ovfn, OVFCAP);
        for (int ii = wv * 64; ii < no; ii += 256) {
            int m = min(64, no - ii);
            uint32 v_l = 0;
            if (lane < m) {
                v_l = ovf[ii + lane];
                if ((v_l >> 19) == (uint32)blockIdx.x)
                    atomicAdd(&dcnt[(v_l >> 16) & 7], 1);
            }
            for (int t = 0; t < m; ++t) {
                uint32 ev = __builtin_amdgcn_readlane(v_l, t);
                if ((ev >> 19) != (uint32)blockIdx.x) continue;
                uint32 v = xb[((ev & 0xffffu) << 6) + lane];
                int r = (ev >> 16) & 7;
                atomicAdd(&a_lds[r][lane],      bfl(v));
                atomicAdd(&a_lds[r][lane + 64], bfh(v));
            }
        }
    }
    __syncthreads();

    // ---- quad gather: wave owns rows {2wv, 2wv+1}; 4 edges per iteration,
    //      unrolled x8 (8 uint4 loads in flight) ----
    const int q  = lane >> 4;
    const int lf = lane & 15;
    const uint4* __restrict__ xb4 = (const uint4*)xb;   // row = 16 uint4

    #pragma unroll
    for (int j = 0; j < 2; ++j) {
        int r  = wv * 2 + j;
        int lo = rst[r];
        int n  = hist8[r];
        int nq = n >> 2;

        float4 aL = make_float4(0.f, 0.f, 0.f, 0.f);
        float4 aH = make_float4(0.f, 0.f, 0.f, 0.f);

        int it = 0;
        for (; it + 8 <= nq; it += 8) {
            int cA = stg[lo + 4 * (it + 0) + q];
            int cB = stg[lo + 4 * (it + 1) + q];
            int cC = stg[lo + 4 * (it + 2) + q];
            int cD = stg[lo + 4 * (it + 3) + q];
            int cE = stg[lo + 4 * (it + 4) + q];
            int cF = stg[lo + 4 * (it + 5) + q];
            int cG = stg[lo + 4 * (it + 6) + q];
            int cH = stg[lo + 4 * (it + 7) + q];
            uint4 vA = xb4[(cA << 4) + lf];
            uint4 vB = xb4[(cB << 4) + lf];
            uint4 vC = xb4[(cC << 4) + lf];
            uint4 vD = xb4[(cD << 4) + lf];
            uint4 vE = xb4[(cE << 4) + lf];
            uint4 vF = xb4[(cF << 4) + lf];
            uint4 vG = xb4[(cG << 4) + lf];
            uint4 vH = xb4[(cH << 4) + lf];
            aL.x += bfl(vA.x); aH.x += bfh(vA.x);
            aL.y += bfl(vA.y); aH.y += bfh(vA.y);
            aL.z += bfl(vA.z); aH.z += bfh(vA.z);
            aL.w += bfl(vA.w); aH.w += bfh(vA.w);
            aL.x += bfl(vB.x); aH.x += bfh(vB.x);
            aL.y += bfl(vB.y); aH.y += bfh(vB.y);
            aL.z += bfl(vB.z); aH.z += bfh(vB.z);
            aL.w += bfl(vB.w); aH.w += bfh(vB.w);
            aL.x += bfl(vC.x); aH.x += bfh(vC.x);
            aL.y += bfl(vC.y); aH.y += bfh(vC.y);
            aL.z += bfl(vC.z); aH.z += bfh(vC.z);
            aL.w += bfl(vC.w); aH.w += bfh(vC.w);
            aL.x += bfl(vD.x); aH.x += bfh(vD.x);
            aL.y += bfl(vD.y); aH.y += bfh(vD.y);
            aL.z += bfl(vD.z); aH.z += bfh(vD.z);
            aL.w += bfl(vD.w); aH.w += bfh(vD.w);
            aL.x += bfl(vE.x); aH.x += bfh(vE.x);
            aL.y += bfl(vE.y); aH.y += bfh(vE.y);
            aL.z += bfl(vE.z); aH.z += bfh(vE.z);
            aL.w += bfl(vE.w); aH.w += bfh(vE.w);
            aL.x += bfl(vF.x); aH.x += bfh(vF.x);
            aL.y += bfl(vF.y); aH.y += bfh(vF.y);
            aL.z += bfl(vF.z); aH.z += bfh(vF.z);
            aL.w += bfl(vF.w); aH.w += bfh(vF.w);
            aL.x += bfl(vG.x); aH.x += bfh(vG.x);
            aL.y += bfl(vG.y); aH.y += bfh(vG.y);
            aL.z += bfl(vG.z); aH.z += bfh(vG.z);
            aL.w += bfl(vG.w); aH.w += bfh(vG.w);
            aL.x += bfl(vH.x); aH.x += bfh(vH.x);
            aL.y += bfl(vH.y); aH.y += bfh(vH.y);
            aL.z += bfl(vH.z); aH.z += bfh(vH.z);
            aL.w += bfl(vH.w); aH.w += bfh(vH.w);
        }
        for (; it < nq; ++it) {
            int c = stg[lo + 4 * it + q];
            uint4 v = xb4[(c << 4) + lf];
            aL.x += bfl(v.x); aH.x += bfh(v.x);
            aL.y += bfl(v.y); aH.y += bfh(v.y);
            aL.z += bfl(v.z); aH.z += bfh(v.z);
            aL.w += bfl(v.w); aH.w += bfh(v.w);
        }
        int rem = n & 3;
        if (q < rem) {     // tail edges handled one per quarter
            int c = stg[lo + 4 * nq + q];
            uint4 v = xb4[(c << 4) + lf];
            aL.x += bfl(v.x); aH.x += bfh(v.x);
            aL.y += bfl(v.y); aH.y += bfh(v.y);
            aL.z += bfl(v.z); aH.z += bfh(v.z);
            aL.w += bfl(v.w); aH.w += bfh(v.w);
        }
        // combine quarters
        aL.x += __shfl_xor(aL.x, 16); aL.x += __shfl_xor(aL.x, 32);
        aL.y += __shfl_xor(aL.y, 16); aL.y += __shfl_xor(aL.y, 32);
        aL.z += __shfl_xor(aL.z, 16); aL.z += __shfl_xor(aL.z, 32);
        aL.w += __shfl_xor(aL.w, 16); aL.w += __shfl_xor(aL.w, 32);
        aH.x += __shfl_xor(aH.x, 16); aH.x += __shfl_xor(aH.x, 32);
        aH.y += __shfl_xor(aH.y, 16); aH.y += __shfl_xor(aH.y, 32);
        aH.z += __shfl_xor(aH.z, 16); aH.z += __shfl_xor(aH.z, 32);
        aH.w += __shfl_xor(aH.w, 16); aH.w += __shfl_xor(aH.w, 32);
        if (q == 0) {      // exclusive (row, lf) per lane: plain RMW
            float4 o0 = *(const float4*)&a_lds[r][4 * lf];
            float4 o1 = *(const float4*)&a_lds[r][4 * lf + 64];
            o0.x += aL.x; o0.y += aL.y; o0.z += aL.z; o0.w += aL.w;
            o1.x += aH.x; o1.y += aH.y; o1.z += aH.z; o1.w += aH.w;
            *(float4*)&a_lds[r][4 * lf]      = o0;
            *(float4*)&a_lds[r][4 * lf + 64] = o1;
        }
    }
    __syncthreads();

    // ---- matvec 1 (k-split): wave wv covers k in [32*wv, 32*wv+32), all rows
    const int f0 = lane, f1 = lane + 64;
    const int k0b = wv * 32;

    float acc0[RPB], acc1[RPB];
    #pragma unroll
    for (int r = 0; r < RPB; ++r) { acc0[r] = 0.f; acc1[r] = 0.f; }

    #pragma unroll
    for (int kk = 0; kk < 32; kk += 4) {
        int k2 = (k0b + kk) >> 1;
        uint32 wm00 = WTmb[k2 * D + f0];
        uint32 wm01 = WTmb[(k2 + 1) * D + f0];
        uint32 wm10 = WTmb[k2 * D + f1];
        uint32 wm11 = WTmb[(k2 + 1) * D + f1];
        float w00l = bfl(wm00), w00h = bfh(wm00), w01l = bfl(wm01), w01h = bfh(wm01);
        float w10l = bfl(wm10), w10h = bfh(wm10), w11l = bfl(wm11), w11h = bfh(wm11);
        #pragma unroll
        for (int r = 0; r < RPB; ++r) {
            float4 a4 = *(const float4*)&a_lds[r][k0b + kk];
            acc0[r] += a4.x * w00l + a4.y * w00h + a4.z * w01l + a4.w * w01h;
            acc1[r] += a4.x * w10l + a4.y * w10h + a4.z * w11l + a4.w * w11h;
        }
    }
    #pragma unroll
    for (int r = 0; r < RPB; ++r) {
        p_lds[wv][r][f0] = acc0[r];
        p_lds[wv][r][f1] = acc1[r];
    }
    __syncthreads();

    // ---- reduce 1 + bias + mean: thread -> (row, 4 features) ----
    {
        int r  = tid >> 5;
        int fq = (tid & 31) * 4;
        float4 s0 = *(const float4*)&p_lds[0][r][fq];
        float4 s1 = *(const float4*)&p_lds[1][r][fq];
        float4 s2 = *(const float4*)&p_lds[2][r][fq];
        float4 s3 = *(const float4*)&p_lds[3][r][fq];
        float cntf = (float)dcnt[r];
        float inv = 1.0f / (cntf + EPS);
        float4 b4 = *(const float4*)&bm[fq];
        float4 o;
        o.x = (s0.x + s1.x + s2.x + s3.x + cntf * b4.x) * inv;
        o.y = (s0.y + s1.y + s2.y + s3.y + cntf * b4.y) * inv;
        o.z = (s0.z + s1.z + s2.z + s3.z + cntf * b4.z) * inv;
        o.w = (s0.w + s1.w + s2.w + s3.w + cntf * b4.w) * inv;
        *(float4*)&o_lds[r][fq] = o;
    }
    __syncthreads();

    // ---- matvec 2 (k-split) ----
    #pragma unroll
    for (int r = 0; r < RPB; ++r) { acc0[r] = 0.f; acc1[r] = 0.f; }

    #pragma unroll
    for (int kk = 0; kk < 32; kk += 4) {
        int k2 = (k0b + kk) >> 1;
        uint32 wu00 = WTub[k2 * D + f0];
        uint32 wu01 = WTub[(k2 + 1) * D + f0];
        uint32 wu10 = WTub[k2 * D + f1];
        uint32 wu11 = WTub[(k2 + 1) * D + f1];
        float w00l = bfl(wu00), w00h = bfh(wu00), w01l = bfl(wu01), w01h = bfh(wu01);
        float w10l = bfl(wu10), w10h = bfh(wu10), w11l = bfl(wu11), w11h = bfh(wu11);
        #pragma unroll
        for (int r = 0; r < RPB; ++r) {
            float4 a4 = *(const float4*)&o_lds[r][k0b + kk];
            acc0[r] += a4.x * w00l + a4.y * w00h + a4.z * w01l + a4.w * w01h;
            acc1[r] += a4.x * w10l + a4.y * w10h + a4.z * w11l + a4.w * w11h;
        }
    }
    __syncthreads();   // reduce-1 reads of p_lds complete before rewrite
    #pragma unroll
    for (int r = 0; r < RPB; ++r) {
        p_lds[wv][r][f0] = acc0[r];
        p_lds[wv][r][f1] = acc1[r];
    }
    __syncthreads();

    // ---- reduce 2 + bias + row-norm + store ----
    {
        int r  = tid >> 5;
        int fq = (tid & 31) * 4;
        float4 s0 = *(const float4*)&p_lds[0][r][fq];
        float4 s1 = *(const float4*)&p_lds[1][r][fq];
        float4 s2 = *(const float4*)&p_lds[2][r][fq];
        float4 s3 = *(const float4*)&p_lds[3][r][fq];
        float4 b4 = *(const float4*)&bu[fq];
        float4 t;
        t.x = s0.x + s1.x + s2.x + s3.x + b4.x;
        t.y = s0.y + s1.y + s2.y + s3.y + b4.y;
        t.z = s0.z + s1.z + s2.z + s3.z + b4.z;
        t.w = s0.w + s1.w + s2.w + s3.w + b4.w;
        float ss = t.x * t.x + t.y * t.y + t.z * t.z + t.w * t.w;
        #pragma unroll
        for (int o = 16; o > 0; o >>= 1) ss += __shfl_xor(ss, o);
        float scale = 1.0f / (sqrtf(ss) + EPS);
        int n = blockIdx.x * RPB + r;
        if (n < N_) {
            float4 w;
            w.x = t.x * scale; w.y = t.y * scale; w.z = t.z * scale; w.w = t.w * scale;
            ((float4*)out)[n * 32 + (tid & 31)] = w;
        }
    }
}

// ---------------- launch ----------------

extern "C" void kernel_launch(void* const* d_in, const int* in_sizes, int n_in,
                              void* d_out, int out_size, void* d_ws, size_t ws_size,
                              hipStream_t stream) {
    const float* x  = (const float*)d_in[0];
    const int*   ei = (const int*)d_in[1];
    const float* Wm = (const float*)d_in[2];
    const float* bm = (const float*)d_in[3];
    const float* Wu = (const float*)d_in[4];
    const float* bu = (const float*)d_in[5];
    float* out = (float*)d_out;

    const int N_ = in_sizes[0] / D;        // 10000
    const int E_ = in_sizes[1] / 2;        // 640000
    const int NX = N_ * (D / 2);           // packed x pairs
    const int NB = (N_ + RPB - 1) / RPB;   // 1250 buckets

    uint32* xb   = (uint32*)d_ws;                 // NX          (16B aligned)
    uint32* eb   = xb + NX;                       // NB*CAP
    uint32* WTmb = eb + (size_t)NB * CAP;         // 64*128
    uint32* WTub = WTmb + 64 * D;                 // 64*128
    int*    bcur = (int*)(WTub + 64 * D);         // NB
    int*    ovfn = bcur + NB;                     // 1
    uint32* ovf  = (uint32*)(ovfn + 1);           // OVFCAP

    k_zero<<<(NB + 1 + 255) / 256, 256, 0, stream>>>(bcur, NB + 1);

    const int nchunk = (E_ + EPB - 1) / EPB;          // 79
    const int npack  = (NX + 511) / 512;              // 1250
    k_stage<<<nchunk + npack, 512, 0, stream>>>(
        x, ei, Wm, Wu, xb, WTmb, WTub, bcur, ovfn, ovf, eb, E_, NX, NB, nchunk);

    k_fused<<<NB, 256, 0, stream>>>(xb, bcur, eb, ovfn, ovf,
                                    WTmb, bm, WTub, bu, out, N_);
}